// Round 13
// baseline (136.539 us; speedup 1.0000x reference)
//
#include <hip/hip_runtime.h>

#define BATCH 65536
#define IN_DIM 128
#define INT_NODES 255
#define LEAF 256
#define OUT_DIM 8
#define ROWS_PB 32                 // 32 rows/block: acc[2][4]=32 AGPRs -> 4-5 waves/SIMD
#define NBLK (BATCH / ROWS_PB)     // 2048 blocks
#define AMB_TH 4e-3f               // fp16-GEMM z error ~3e-4 RMS; wide guard band

typedef float    f4v __attribute__((ext_vector_type(4)));
typedef _Float16 h8v __attribute__((ext_vector_type(8)));

// Prepass: blocks [0,64) = LDS-tiled transpose Wor -> Wor_t[l][o][i];
// blocks [64,192) = Wp -> fp16 MFMA B-fragments (node 255 zero-pad).
__global__ __launch_bounds__(256) void prep(const float* __restrict__ Wor,
                                            float* __restrict__ Wor_t,
                                            const float* __restrict__ Wp,
                                            _Float16* __restrict__ Bf) {
    if (blockIdx.x < 64) {
        __shared__ float t[64][65];
        const int rt = blockIdx.x >> 2, ct = blockIdx.x & 3;  // 16 x 4 tiles of 64x64
        const int r0 = rt * 64, c0 = ct * 64;
        const int tx = threadIdx.x & 63, ty = threadIdx.x >> 6;
#pragma unroll
        for (int p = 0; p < 16; ++p) {
            int r = ty + p * 4;
            t[r][tx] = Wor[(size_t)(r0 + r) * 256 + c0 + tx];     // coalesced
        }
        __syncthreads();
#pragma unroll
        for (int p = 0; p < 16; ++p) {
            int r = ty + p * 4;
            Wor_t[(size_t)(c0 + r) * 1024 + r0 + tx] = t[tx][r];  // coalesced
        }
    } else {
        // B-frag (16x16x32): B[k = ks*32+(lane>>4)*8+j][n = ntg*16+(lane&15)],
        // slot = ((ks*16+ntg)*64+lane)*8+j.
        int slot = (blockIdx.x - 64) * 256 + threadIdx.x;   // 32768
        int j    = slot & 7;
        int lane = (slot >> 3) & 63;
        int ntg  = (slot >> 9) & 15;
        int ks   = slot >> 13;
        int n = ntg * 16 + (lane & 15);
        int k = ks * 32 + (lane >> 4) * 8 + j;
        float v = (n < INT_NODES) ? Wp[n * IN_DIM + k] : 0.f;
        Bf[slot] = (_Float16)v;
    }
}

// Fused main. Block = 256 threads = 32 rows. Wave w: node cols [64w,64w+64),
// rows 0..31 -> acc[2][4] = 32 AGPRs (R12's 64-AGPR acc capped the unified
// reg file at 2 waves/SIMD -> 18% occupancy; this is the fix).
__global__ __launch_bounds__(256) void dgt_main(
    const float* __restrict__ x, const float* __restrict__ Wp,
    const float* __restrict__ bp, const _Float16* __restrict__ Bfg,
    const float* __restrict__ Wor_t, const float* __restrict__ bor,
    const float* __restrict__ stds,
    float* __restrict__ out, float* __restrict__ stdo) {

    __shared__ unsigned char sgn[LEAF * 8];   // 2KB: code(n,m) -> sgn[n*8+(m>>2)] >> (m&3)*2
    __shared__ float P[64 * 36];              // 9.2KB: |z| partials [(w*16+c)*36 + m]
    __shared__ float S[8 * 32];               // 1KB: [q*32 + r] eighth-sums
    __shared__ float H[32 * 68];              // 8.7KB: heads partials [r*68 + o*8 + kq]
    __shared__ float psL[32];
    __shared__ int   leafL[32];

    const int tid  = threadIdx.x;
    const int wave = tid >> 6;
    const int lane = tid & 63;
    const int c = lane & 15;
    const int g = lane >> 4;
    const int rowbase = blockIdx.x * ROWS_PB;

    // ---- phase 1: fp16 MFMA (32 rows x 64 node-cols per wave) ----
    f4v acc[2][4];
#pragma unroll
    for (int mt = 0; mt < 2; ++mt)
#pragma unroll
        for (int nt = 0; nt < 4; ++nt) acc[mt][nt] = (f4v){0.f, 0.f, 0.f, 0.f};

    const h8v* Bf8 = (const h8v*)Bfg;
    const float* xbase = x + (size_t)rowbase * IN_DIM;
#pragma unroll
    for (int ks = 0; ks < 4; ++ks) {
        h8v ah[2];
#pragma unroll
        for (int mt = 0; mt < 2; ++mt) {
            const float* p = xbase + (size_t)(mt * 16 + c) * IN_DIM + ks * 32 + g * 8;
            float4 v0 = *reinterpret_cast<const float4*>(p);
            float4 v1 = *reinterpret_cast<const float4*>(p + 4);
            h8v a;
            a[0] = (_Float16)v0.x; a[1] = (_Float16)v0.y;
            a[2] = (_Float16)v0.z; a[3] = (_Float16)v0.w;
            a[4] = (_Float16)v1.x; a[5] = (_Float16)v1.y;
            a[6] = (_Float16)v1.z; a[7] = (_Float16)v1.w;
            ah[mt] = a;
        }
#pragma unroll
        for (int nt = 0; nt < 4; ++nt) {
            h8v b = Bf8[(ks * 16 + (wave * 4 + nt)) * 64 + lane];  // coalesced, L2-hot
#pragma unroll
            for (int mt = 0; mt < 2; ++mt)
                acc[mt][nt] = __builtin_amdgcn_mfma_f32_16x16x32_f16(ah[mt], b, acc[mt][nt], 0, 0, 0);
        }
    }

    // ---- phase 2: compress -> sgn LDS + |z+bp| partials -> P LDS ----
    // C/D: col n = wave*64 + nt*16 + c, row m = mt*16 + g*4 + rr (m in 0..31).
    {
        float pp[2][4];
#pragma unroll
        for (int mt = 0; mt < 2; ++mt)
#pragma unroll
            for (int rr = 0; rr < 4; ++rr) pp[mt][rr] = 0.f;
#pragma unroll
        for (int nt = 0; nt < 4; ++nt) {
            const int n = wave * 64 + nt * 16 + c;
            const float bpv = (n < INT_NODES) ? bp[n] : 0.f;   // 1KB, L1-hot
#pragma unroll
            for (int mt = 0; mt < 2; ++mt) {
                unsigned by = 0;
#pragma unroll
                for (int rr = 0; rr < 4; ++rr) {
                    float v = acc[mt][nt][rr] + bpv;
                    float av = fabsf(v);
                    if (n < INT_NODES) pp[mt][rr] += av;
                    by |= ((v < 0.f ? 1u : 0u) | (av < AMB_TH ? 2u : 0u)) << (2 * rr);
                }
                sgn[n * 8 + mt * 4 + g] = (unsigned char)by;
            }
        }
#pragma unroll
        for (int mt = 0; mt < 2; ++mt)
#pragma unroll
            for (int rr = 0; rr < 4; ++rr)
                P[(wave * 16 + c) * 36 + mt * 16 + g * 4 + rr] = pp[mt][rr];
    }
    __syncthreads();   // #1

    // ---- phase 3: reduce P over 64 col-chunks: thread (r = tid&31, q = tid>>5) ----
    {
        const int r = tid & 31, q = tid >> 5;   // q: 8 groups of 8 chunks
        float s = 0.f;
#pragma unroll
        for (int cc = 0; cc < 8; ++cc) s += P[(q * 8 + cc) * 36 + r];
        S[q * 32 + r] = s;
    }
    __syncthreads();   // #2

    // ---- phase 4: traversal (x8 redundant) + heads partials.
    //      thread = (row r = tid>>3, K-eighth kq = tid&7). ----
    {
        const int r = tid >> 3, kq = tid & 7;
        float asum = 0.f;
#pragma unroll
        for (int j = 0; j < 8; ++j) asum += S[j * 32 + r];
        const float fac = asum * (1.0f / (float)INT_NODES);
        // p* of argmax leaf: sum_l exp(and_z_l - 8 fac) = (1 + e^{-2 fac})^8.
        const float e = expf(-2.0f * fac);
        const float qq = 1.0f + e;
        const float q2 = qq * qq, q4 = q2 * q2, q8 = q4 * q4;
        const float ps = 1.0f / q8;

        int node = 0;
#pragma unroll
        for (int d = 0; d < 8; ++d) {
            unsigned by = sgn[node * 8 + (r >> 2)];
            int code = (int)((by >> ((r & 3) * 2)) & 3u);
            int neg;
            if (code & 2) {          // rare: exact sign via fp64 from global
                double zd = (double)bp[node];
                const float* wr = Wp + node * IN_DIM;
                const float* xrow = x + (size_t)(rowbase + r) * IN_DIM;
                for (int k = 0; k < IN_DIM; ++k)
                    zd = fma((double)wr[k], (double)xrow[k], zd);
                neg = (zd < 0.0) ? 1 : 0;
            } else {
                neg = code & 1;
            }
            node = 2 * node + 1 + neg;
        }
        const int leaf = node - INT_NODES;
        if (kq == 0) { psL[r] = ps; leafL[r] = leaf; }

        // heads partials: thread kq owns float4 chunks (step*8+kq), step 0..3.
        // 8 kq lanes cover 128B contiguous of the same leaf slice -> 2 lines/row.
        const float* xr = x + (size_t)(rowbase + r) * IN_DIM;    // L1-hot
        const float* wl = Wor_t + (size_t)leaf * 1024;
        float hp[8], tp[8];
#pragma unroll
        for (int o = 0; o < 8; ++o) { hp[o] = 0.f; tp[o] = 0.f; }
#pragma unroll
        for (int step = 0; step < 4; ++step) {
            const int off = (step * 8 + kq) * 4;
            float4 xv = *reinterpret_cast<const float4*>(xr + off);
#pragma unroll
            for (int o = 0; o < 8; ++o) {
                float4 wv = *reinterpret_cast<const float4*>(wl + o * IN_DIM + off);
                float4 bv = *reinterpret_cast<const float4*>(bor + o * IN_DIM + off);
                hp[o] = fmaf(wv.x, xv.x, hp[o]); hp[o] = fmaf(wv.y, xv.y, hp[o]);
                hp[o] = fmaf(wv.z, xv.z, hp[o]); hp[o] = fmaf(wv.w, xv.w, hp[o]);
                tp[o] = fmaf(bv.x, xv.x, tp[o]); tp[o] = fmaf(bv.y, xv.y, tp[o]);
                tp[o] = fmaf(bv.z, xv.z, tp[o]); tp[o] = fmaf(bv.w, xv.w, tp[o]);
            }
        }
#pragma unroll
        for (int o = 0; o < 8; ++o)
            H[r * 68 + o * 8 + kq] = ps * hp[o] + tp[o];
    }
    __syncthreads();   // #3

    // ---- phase 5: final reduce + stores: thread (r = tid&31, o = tid>>5) ----
    {
        const int r = tid & 31, o = tid >> 5;
        const float* h = &H[r * 68 + o * 8];
        float v = ((h[0] + h[1]) + (h[2] + h[3])) + ((h[4] + h[5]) + (h[6] + h[7]));
        out[(size_t)(rowbase + r) * OUT_DIM + o] = v;
        float sd = psL[r] * stds[leafL[r] * OUT_DIM + o];
        stdo[(size_t)(rowbase + r) * OUT_DIM + o] = fminf(fmaxf(sd, -20.0f), 2.0f);
    }
}

extern "C" void kernel_launch(void* const* d_in, const int* in_sizes, int n_in,
                              void* d_out, int out_size, void* d_ws, size_t ws_size,
                              hipStream_t stream) {
    const float* x    = (const float*)d_in[0];
    const float* Wp   = (const float*)d_in[1];
    const float* bp   = (const float*)d_in[2];
    // d_in[3] = Wand -- folded into the traversal, unused.
    const float* Wor  = (const float*)d_in[4];
    const float* bor  = (const float*)d_in[5];
    const float* stds = (const float*)d_in[6];
    float* out = (float*)d_out;

    char* ws = (char*)d_ws;
    float* wor_t = (float*)(ws);                  // 1 MB
    _Float16* Bf = (_Float16*)(ws + (1 << 20));   // 64 KB

    prep<<<192, 256, 0, stream>>>(Wor, wor_t, Wp, Bf);
    dgt_main<<<NBLK, 256, 0, stream>>>(x, Wp, bp, Bf, wor_t, bor, stds,
                                       out, out + (size_t)BATCH * OUT_DIM);
}

// Round 14
// 122.277 us; speedup vs baseline: 1.1166x; 1.1166x over previous
//
#include <hip/hip_runtime.h>

#define BATCH 65536
#define IN_DIM 128
#define INT_NODES 255
#define LEAF 256
#define OUT_DIM 8
#define AMB_TH 4e-3f   // fp16-GEMM z error ~3e-4 RMS; wide guard band

typedef float    f4v __attribute__((ext_vector_type(4)));
typedef _Float16 h8v __attribute__((ext_vector_type(8)));

#define LGKM0() __asm__ volatile("s_waitcnt lgkmcnt(0)" ::: "memory")

// Prepass: blocks [0,64) = LDS-tiled transpose Wor -> Wor_t[l][o][i];
// blocks [64,192) = Wp -> fp16 MFMA B-fragments (node 255 zero-pad).
__global__ __launch_bounds__(256) void prep(const float* __restrict__ Wor,
                                            float* __restrict__ Wor_t,
                                            const float* __restrict__ Wp,
                                            _Float16* __restrict__ Bf) {
    if (blockIdx.x < 64) {
        __shared__ float t[64][65];
        const int rt = blockIdx.x >> 2, ct = blockIdx.x & 3;  // 16 x 4 tiles of 64x64
        const int r0 = rt * 64, c0 = ct * 64;
        const int tx = threadIdx.x & 63, ty = threadIdx.x >> 6;
#pragma unroll
        for (int p = 0; p < 16; ++p) {
            int r = ty + p * 4;
            t[r][tx] = Wor[(size_t)(r0 + r) * 256 + c0 + tx];     // coalesced
        }
        __syncthreads();
#pragma unroll
        for (int p = 0; p < 16; ++p) {
            int r = ty + p * 4;
            Wor_t[(size_t)(c0 + r) * 1024 + r0 + tx] = t[tx][r];  // coalesced
        }
    } else {
        // B-frag (16x16x32): B[k = ks*32+(lane>>4)*8+j][n = ntg*16+(lane&15)],
        // slot = ((ks*16+ntg)*64+lane)*8+j.
        int slot = (blockIdx.x - 64) * 256 + threadIdx.x;   // 32768
        int j    = slot & 7;
        int lane = (slot >> 3) & 63;
        int ntg  = (slot >> 9) & 15;
        int ks   = slot >> 13;
        int n = ntg * 16 + (lane & 15);
        int k = ks * 32 + (lane >> 4) * 8 + j;
        float v = (n < INT_NODES) ? Wp[n * IN_DIM + k] : 0.f;
        Bf[slot] = (_Float16)v;
    }
}

// ZERO-BARRIER fused main. Wave = 16 rows x ALL 256 nodes, fully independent
// (R12/R13 proved time is barrier-structure-bound, not residency-bound: all
// waves in a block rode the slowest phase). All LDS is wave-private; ordering
// via lgkmcnt only. acc[8]+ah[4] keeps regs ~100 -> ~5 waves/SIMD.
__global__ __launch_bounds__(256) void dgt_main(
    const float* __restrict__ x, const float* __restrict__ Wp,
    const float* __restrict__ bp, const _Float16* __restrict__ Bfg,
    const float* __restrict__ Wor_t, const float* __restrict__ bor,
    const float* __restrict__ stds,
    float* __restrict__ out, float* __restrict__ stdo) {

    __shared__ unsigned char sgnS[4][LEAF * 4];  // [wave][n*4 + g]: codes for rows g*4+rr
    __shared__ float asumS[4][16 * 16];          // [wave][row*16 + c]
    __shared__ float hdS[4][16 * 36];            // [wave][r*36 + o*4 + kq]
    __shared__ float psS[4][16];
    __shared__ int   lfS[4][16];

    const int tid  = threadIdx.x;
    const int wave = tid >> 6;
    const int lane = tid & 63;
    const int c = lane & 15;          // row within wave strip / B-col n low bits
    const int g = lane >> 4;          // k-group
    const int rowbase = blockIdx.x * 64 + wave * 16;

    unsigned char* sgn = sgnS[wave];
    float* asum = asumS[wave];
    float* hd = hdS[wave];

    // ---- A-fragments for all 4 k-steps (cached: 16 VGPRs) ----
    h8v ah[4];
    {
        const float* xb = x + (size_t)(rowbase + c) * IN_DIM;
#pragma unroll
        for (int ks = 0; ks < 4; ++ks) {
            const float* p = xb + ks * 32 + g * 8;
            float4 v0 = *reinterpret_cast<const float4*>(p);
            float4 v1 = *reinterpret_cast<const float4*>(p + 4);
            h8v a;
            a[0] = (_Float16)v0.x; a[1] = (_Float16)v0.y;
            a[2] = (_Float16)v0.z; a[3] = (_Float16)v0.w;
            a[4] = (_Float16)v1.x; a[5] = (_Float16)v1.y;
            a[6] = (_Float16)v1.z; a[7] = (_Float16)v1.w;
            ah[ks] = a;
        }
    }

    // ---- GEMM + compress, two 128-col halves (acc[8] = 32 AGPRs) ----
    const h8v* Bf8 = (const h8v*)Bfg;
    float pp[4] = {0.f, 0.f, 0.f, 0.f};
#pragma unroll
    for (int h = 0; h < 2; ++h) {
        f4v acc[8];
#pragma unroll
        for (int nt = 0; nt < 8; ++nt) acc[nt] = (f4v){0.f, 0.f, 0.f, 0.f};
#pragma unroll
        for (int ks = 0; ks < 4; ++ks)
#pragma unroll
            for (int nt = 0; nt < 8; ++nt) {
                h8v b = Bf8[(ks * 16 + h * 8 + nt) * 64 + lane];  // 1KB coalesced, L2-hot
                acc[nt] = __builtin_amdgcn_mfma_f32_16x16x32_f16(ah[ks], b, acc[nt], 0, 0, 0);
            }
        // compress this half: C/D col n = h*128 + nt*16 + c, row m = g*4 + rr
#pragma unroll
        for (int nt = 0; nt < 8; ++nt) {
            const int n = h * 128 + nt * 16 + c;
            const float bpv = (n < INT_NODES) ? bp[n] : 0.f;   // 1KB, L1-hot
            unsigned by = 0;
#pragma unroll
            for (int rr = 0; rr < 4; ++rr) {
                float v = acc[nt][rr] + bpv;
                float av = fabsf(v);
                if (n < INT_NODES) pp[rr] += av;
                by |= ((v < 0.f ? 1u : 0u) | (av < AMB_TH ? 2u : 0u)) << (2 * rr);
            }
            sgn[n * 4 + g] = (unsigned char)by;
        }
    }
    // |z| partials -> LDS transposed [row][c] (reads become ds_read_b128)
#pragma unroll
    for (int rr = 0; rr < 4; ++rr) asum[(g * 4 + rr) * 16 + c] = pp[rr];
    LGKM0();

    // ---- traversal + p*: lanes 0..15 (one row each; same wave, no barrier) ----
    if (lane < 16) {
        const int r = lane;
        float s = 0.f;
#pragma unroll
        for (int cc = 0; cc < 16; cc += 4) {
            f4v v = *reinterpret_cast<f4v*>(&asum[r * 16 + cc]);
            s += (v[0] + v[1]) + (v[2] + v[3]);
        }
        const float fac = s * (1.0f / (float)INT_NODES);
        // p* of argmax leaf: sum_l exp(and_z_l - 8 fac) = (1 + e^{-2 fac})^8.
        const float e = expf(-2.0f * fac);
        const float q = 1.0f + e;
        const float q2 = q * q, q4 = q2 * q2, q8 = q4 * q4;

        int node = 0;
#pragma unroll
        for (int d = 0; d < 8; ++d) {
            unsigned by = sgn[node * 4 + (r >> 2)];
            int code = (int)((by >> ((r & 3) * 2)) & 3u);
            int neg;
            if (code & 2) {          // rare: exact sign via fp64 from global
                double zd = (double)bp[node];
                const float* wr = Wp + node * IN_DIM;
                const float* xrow = x + (size_t)(rowbase + r) * IN_DIM;
                for (int k = 0; k < IN_DIM; ++k)
                    zd = fma((double)wr[k], (double)xrow[k], zd);
                neg = (zd < 0.0) ? 1 : 0;
            } else {
                neg = code & 1;
            }
            node = 2 * node + 1 + neg;
        }
        psS[wave][r] = 1.0f / q8;
        lfS[wave][r] = node - INT_NODES;
    }
    LGKM0();

    // ---- heads: lane = (row r = lane>>2, K-quarter kq = lane&3).
    //      Chunk index (step*4+kq): 4 kq lanes cover one 64B line -> each line
    //      of the leaf slice requested exactly once (64 lines/row floor). ----
    {
        const int r = lane >> 2, kq = lane & 3;
        const int leaf = lfS[wave][r];
        const float ps = psS[wave][r];
        const float* xr = x + (size_t)(rowbase + r) * IN_DIM;   // L1-hot
        const float* wl = Wor_t + (size_t)leaf * 1024;
        float hp[8], tp[8];
#pragma unroll
        for (int o = 0; o < 8; ++o) { hp[o] = 0.f; tp[o] = 0.f; }
#pragma unroll
        for (int step = 0; step < 8; ++step) {
            const int off = (step * 4 + kq) * 4;
            float4 xv = *reinterpret_cast<const float4*>(xr + off);
#pragma unroll
            for (int o = 0; o < 8; ++o) {
                float4 wv = *reinterpret_cast<const float4*>(wl + o * IN_DIM + off);
                float4 bv = *reinterpret_cast<const float4*>(bor + o * IN_DIM + off);
                hp[o] = fmaf(wv.x, xv.x, hp[o]); hp[o] = fmaf(wv.y, xv.y, hp[o]);
                hp[o] = fmaf(wv.z, xv.z, hp[o]); hp[o] = fmaf(wv.w, xv.w, hp[o]);
                tp[o] = fmaf(bv.x, xv.x, tp[o]); tp[o] = fmaf(bv.y, xv.y, tp[o]);
                tp[o] = fmaf(bv.z, xv.z, tp[o]); tp[o] = fmaf(bv.w, xv.w, tp[o]);
            }
        }
#pragma unroll
        for (int o = 0; o < 8; ++o)
            hd[r * 36 + o * 4 + kq] = ps * hp[o] + tp[o];
    }
    LGKM0();

    // ---- final reduce + stores: lane = (row r = lane>>2, o-pair op = lane&3) ----
    {
        const int r = lane >> 2, op = lane & 3, o0 = op * 2;
        f4v a = *reinterpret_cast<f4v*>(&hd[r * 36 + o0 * 4]);
        f4v b = *reinterpret_cast<f4v*>(&hd[r * 36 + o0 * 4 + 4]);
        float2 ov;
        ov.x = (a[0] + a[1]) + (a[2] + a[3]);
        ov.y = (b[0] + b[1]) + (b[2] + b[3]);
        const size_t ob = (size_t)(rowbase + r) * OUT_DIM + o0;
        *reinterpret_cast<float2*>(out + ob) = ov;
        const int leaf = lfS[wave][r];
        const float ps = psS[wave][r];
        float2 sv;
        sv.x = fminf(fmaxf(ps * stds[leaf * OUT_DIM + o0],     -20.0f), 2.0f);
        sv.y = fminf(fmaxf(ps * stds[leaf * OUT_DIM + o0 + 1], -20.0f), 2.0f);
        *reinterpret_cast<float2*>(stdo + ob) = sv;
    }
}

extern "C" void kernel_launch(void* const* d_in, const int* in_sizes, int n_in,
                              void* d_out, int out_size, void* d_ws, size_t ws_size,
                              hipStream_t stream) {
    const float* x    = (const float*)d_in[0];
    const float* Wp   = (const float*)d_in[1];
    const float* bp   = (const float*)d_in[2];
    // d_in[3] = Wand -- folded into the traversal, unused.
    const float* Wor  = (const float*)d_in[4];
    const float* bor  = (const float*)d_in[5];
    const float* stds = (const float*)d_in[6];
    float* out = (float*)d_out;

    char* ws = (char*)d_ws;
    float* wor_t = (float*)(ws);                  // 1 MB
    _Float16* Bf = (_Float16*)(ws + (1 << 20));   // 64 KB

    prep<<<192, 256, 0, stream>>>(Wor, wor_t, Wp, Bf);
    dgt_main<<<BATCH / 64, 256, 0, stream>>>(x, Wp, bp, Bf, wor_t, bor, stds,
                                             out, out + (size_t)BATCH * OUT_DIM);
}

// Round 16
// 113.189 us; speedup vs baseline: 1.2063x; 1.0803x over previous
//
#include <hip/hip_runtime.h>

#define BATCH 65536
#define IN_DIM 128
#define INT_NODES 255
#define LEAF 256
#define OUT_DIM 8
#define AMB_TH 4e-3f   // fp16-GEMM z error ~3e-4 RMS; wide guard band

typedef float    f4v __attribute__((ext_vector_type(4)));
typedef _Float16 h8v __attribute__((ext_vector_type(8)));
typedef _Float16 h2v __attribute__((ext_vector_type(2)));

#define LGKM0() __asm__ volatile("s_waitcnt lgkmcnt(0)" ::: "memory")

__device__ __forceinline__ float fdot2(h2v a, h2v b, float c) {
#if __has_builtin(__builtin_amdgcn_fdot2)
    return __builtin_amdgcn_fdot2(a, b, c, false);
#else
    return c + (float)a[0] * (float)b[0] + (float)a[1] * (float)b[1];
#endif
}

// Prepass: blocks [0,64) LDS-tiled transpose Wor -> Wh fp16 [l][o*128+i];
// blocks [64,192) Wp -> fp16 B-frags; blocks [192,200) bor -> fp16 B-frag.
__global__ __launch_bounds__(256) void prep(const float* __restrict__ Wor,
                                            _Float16* __restrict__ Wh,
                                            const float* __restrict__ Wp,
                                            _Float16* __restrict__ Bf,
                                            const float* __restrict__ bor,
                                            _Float16* __restrict__ Bb) {
    if (blockIdx.x < 64) {
        __shared__ float t[64][65];
        const int rt = blockIdx.x >> 2, ct = blockIdx.x & 3;  // 16 x 4 tiles of 64x64
        const int r0 = rt * 64, c0 = ct * 64;
        const int tx = threadIdx.x & 63, ty = threadIdx.x >> 6;
#pragma unroll
        for (int p = 0; p < 16; ++p) {
            int r = ty + p * 4;
            t[r][tx] = Wor[(size_t)(r0 + r) * 256 + c0 + tx];     // coalesced
        }
        __syncthreads();
#pragma unroll
        for (int p = 0; p < 16; ++p) {
            int r = ty + p * 4;
            Wh[(size_t)(c0 + r) * 1024 + r0 + tx] = (_Float16)t[tx][r];  // coalesced
        }
    } else if (blockIdx.x < 192) {
        // B-frag (16x16x32): B[k=ks*32+(lane>>4)*8+j][n=ntg*16+(lane&15)],
        // slot = ((ks*16+ntg)*64+lane)*8+j.
        int slot = (blockIdx.x - 64) * 256 + threadIdx.x;   // 32768
        int j    = slot & 7;
        int lane = (slot >> 3) & 63;
        int ntg  = (slot >> 9) & 15;
        int ks   = slot >> 13;
        int n = ntg * 16 + (lane & 15);
        int k = ks * 32 + (lane >> 4) * 8 + j;
        float v = (n < INT_NODES) ? Wp[n * IN_DIM + k] : 0.f;
        Bf[slot] = (_Float16)v;
    } else {
        // bor B-frag: one 16-col tile (cols 0..7 = outputs), slot=(ks*64+lane)*8+j
        int slot = (blockIdx.x - 192) * 256 + threadIdx.x;  // 2048
        int j    = slot & 7;
        int lane = (slot >> 3) & 63;
        int ks   = slot >> 9;
        int o = lane & 15;
        int k = ks * 32 + (lane >> 4) * 8 + j;
        float v = (o < OUT_DIM) ? bor[o * IN_DIM + k] : 0.f;
        Bb[slot] = (_Float16)v;
    }
}

// Zero-barrier fused main (R14 structure). Wave = 16 rows x 256 nodes.
// R16 deltas vs R14: fp16 Wor gather (halves heads line-lookups), bor head via
// MFMA (removes 1024 L1 re-lookups/wave), heads-x prefetch overlaps the
// traversal LDS chain, 4-chain fp64 rescue.
__global__ __launch_bounds__(256) void dgt_main(
    const float* __restrict__ x, const float* __restrict__ Wp,
    const float* __restrict__ bp, const _Float16* __restrict__ Bfg,
    const _Float16* __restrict__ Bbg, const _Float16* __restrict__ Wh,
    const float* __restrict__ stds,
    float* __restrict__ out, float* __restrict__ stdo) {

    __shared__ unsigned char sgnS[4][LEAF * 4];  // [wave][n*4+g]: codes rows g*4+rr
    __shared__ float asumS[4][16 * 16];          // [wave][row*16 + c]
    __shared__ float hdS[4][16 * 36];            // [wave][r*36 + o*4 + kq]
    __shared__ float tbS[4][16 * 8];             // [wave][r*8 + o]: <bor,x>
    __shared__ float psS[4][16];
    __shared__ int   lfS[4][16];

    const int tid  = threadIdx.x;
    const int wave = tid >> 6;
    const int lane = tid & 63;
    const int c = lane & 15;
    const int g = lane >> 4;
    const int rowbase = blockIdx.x * 64 + wave * 16;

    unsigned char* sgn = sgnS[wave];
    float* asum = asumS[wave];
    float* hd = hdS[wave];

    // ---- A-fragments for all 4 k-steps (16 VGPRs) ----
    h8v ah[4];
    {
        const float* xb = x + (size_t)(rowbase + c) * IN_DIM;
#pragma unroll
        for (int ks = 0; ks < 4; ++ks) {
            const float* p = xb + ks * 32 + g * 8;
            float4 v0 = *reinterpret_cast<const float4*>(p);
            float4 v1 = *reinterpret_cast<const float4*>(p + 4);
            h8v a;
            a[0] = (_Float16)v0.x; a[1] = (_Float16)v0.y;
            a[2] = (_Float16)v0.z; a[3] = (_Float16)v0.w;
            a[4] = (_Float16)v1.x; a[5] = (_Float16)v1.y;
            a[6] = (_Float16)v1.z; a[7] = (_Float16)v1.w;
            ah[ks] = a;
        }
    }

    // ---- bor head via MFMA (leaf-independent, reuses ah) ----
    {
        const h8v* Bb8 = (const h8v*)Bbg;
        f4v tb = (f4v){0.f, 0.f, 0.f, 0.f};
#pragma unroll
        for (int ks = 0; ks < 4; ++ks)
            tb = __builtin_amdgcn_mfma_f32_16x16x32_f16(ah[ks], Bb8[ks * 64 + lane], tb, 0, 0, 0);
        if (c < OUT_DIM) {
#pragma unroll
            for (int rr = 0; rr < 4; ++rr)
                tbS[wave][(g * 4 + rr) * 8 + c] = tb[rr];
        }
    }

    // ---- GEMM + compress, two 128-col halves (acc[8] = 32 AGPRs) ----
    const h8v* Bf8 = (const h8v*)Bfg;
    float pp[4] = {0.f, 0.f, 0.f, 0.f};
#pragma unroll
    for (int h = 0; h < 2; ++h) {
        f4v acc[8];
#pragma unroll
        for (int nt = 0; nt < 8; ++nt) acc[nt] = (f4v){0.f, 0.f, 0.f, 0.f};
#pragma unroll
        for (int ks = 0; ks < 4; ++ks)
#pragma unroll
            for (int nt = 0; nt < 8; ++nt) {
                h8v b = Bf8[(ks * 16 + h * 8 + nt) * 64 + lane];  // coalesced, L2-hot
                acc[nt] = __builtin_amdgcn_mfma_f32_16x16x32_f16(ah[ks], b, acc[nt], 0, 0, 0);
            }
        // compress: C/D col n = h*128 + nt*16 + c, row m = g*4 + rr
#pragma unroll
        for (int nt = 0; nt < 8; ++nt) {
            const int n = h * 128 + nt * 16 + c;
            const float bpv = (n < INT_NODES) ? bp[n] : 0.f;   // 1KB, L1-hot
            unsigned by = 0;
#pragma unroll
            for (int rr = 0; rr < 4; ++rr) {
                float v = acc[nt][rr] + bpv;
                float av = fabsf(v);
                if (n < INT_NODES) pp[rr] += av;
                by |= ((v < 0.f ? 1u : 0u) | (av < AMB_TH ? 2u : 0u)) << (2 * rr);
            }
            sgn[n * 4 + g] = (unsigned char)by;
        }
    }
#pragma unroll
    for (int rr = 0; rr < 4; ++rr) asum[(g * 4 + rr) * 16 + c] = pp[rr];

    // ---- heads-x prefetch (leaf-independent; overlaps traversal chain) ----
    h2v xh[16];
    {
        const float* xr = x + (size_t)(rowbase + (lane >> 2)) * IN_DIM;
        const int kq = lane & 3;
#pragma unroll
        for (int ch = 0; ch < 4; ++ch) {
            const int base = (ch * 4 + kq) * 8;
            float4 v0 = *reinterpret_cast<const float4*>(xr + base);
            float4 v1 = *reinterpret_cast<const float4*>(xr + base + 4);
            xh[ch * 4 + 0] = (h2v){(_Float16)v0.x, (_Float16)v0.y};
            xh[ch * 4 + 1] = (h2v){(_Float16)v0.z, (_Float16)v0.w};
            xh[ch * 4 + 2] = (h2v){(_Float16)v1.x, (_Float16)v1.y};
            xh[ch * 4 + 3] = (h2v){(_Float16)v1.z, (_Float16)v1.w};
        }
    }
    LGKM0();   // sgn/asum/tb visible (same wave)

    // ---- traversal + p*: lanes 0..15, one row each ----
    if (lane < 16) {
        const int r = lane;
        float s = 0.f;
#pragma unroll
        for (int cc = 0; cc < 16; cc += 4) {
            f4v v = *reinterpret_cast<f4v*>(&asum[r * 16 + cc]);
            s += (v[0] + v[1]) + (v[2] + v[3]);
        }
        const float fac = s * (1.0f / (float)INT_NODES);
        // p* of argmax leaf: sum_l exp(and_z_l - 8 fac) = (1 + e^{-2 fac})^8.
        const float e = expf(-2.0f * fac);
        const float q = 1.0f + e;
        const float q2 = q * q, q4 = q2 * q2, q8 = q4 * q4;

        int node = 0;
#pragma unroll
        for (int d = 0; d < 8; ++d) {
            unsigned by = sgn[node * 4 + (r >> 2)];
            int code = (int)((by >> ((r & 3) * 2)) & 3u);
            int neg;
            if (code & 2) {          // rare: exact sign via fp64, 4 chains
                const float* wr = Wp + node * IN_DIM;
                const float* xrow = x + (size_t)(rowbase + r) * IN_DIM;
                double z0 = 0.0, z1 = 0.0, z2 = 0.0, z3 = 0.0;
                for (int k = 0; k < IN_DIM; k += 4) {
                    float4 wv = *reinterpret_cast<const float4*>(wr + k);
                    float4 xv = *reinterpret_cast<const float4*>(xrow + k);
                    z0 = fma((double)wv.x, (double)xv.x, z0);
                    z1 = fma((double)wv.y, (double)xv.y, z1);
                    z2 = fma((double)wv.z, (double)xv.z, z2);
                    z3 = fma((double)wv.w, (double)xv.w, z3);
                }
                double zd = ((z0 + z1) + (z2 + z3)) + (double)bp[node];
                neg = (zd < 0.0) ? 1 : 0;
            } else {
                neg = code & 1;
            }
            node = 2 * node + 1 + neg;
        }
        psS[wave][r] = 1.0f / q8;
        lfS[wave][r] = node - INT_NODES;
    }
    LGKM0();

    // ---- heads: lane = (row r, K-quarter kq); fp16 gather + fdot2.
    //      Chunk (ch*4+kq): 4 kq lanes cover one 64B line of the 2KB slice. ----
    {
        const int r = lane >> 2, kq = lane & 3;
        const int leaf = lfS[wave][r];
        const _Float16* wl = Wh + (size_t)leaf * 1024;
        float hp[8];
#pragma unroll
        for (int o = 0; o < 8; ++o) hp[o] = 0.f;
#pragma unroll
        for (int ch = 0; ch < 4; ++ch) {
            const int base = (ch * 4 + kq) * 8;
            h2v x0 = xh[ch * 4 + 0], x1 = xh[ch * 4 + 1];
            h2v x2 = xh[ch * 4 + 2], x3 = xh[ch * 4 + 3];
#pragma unroll
            for (int o = 0; o < 8; ++o) {
                h8v w8 = *reinterpret_cast<const h8v*>(wl + o * IN_DIM + base);
                h2v w0 = {w8[0], w8[1]}, w1 = {w8[2], w8[3]};
                h2v w2 = {w8[4], w8[5]}, w3 = {w8[6], w8[7]};
                hp[o] = fdot2(w0, x0, hp[o]);
                hp[o] = fdot2(w1, x1, hp[o]);
                hp[o] = fdot2(w2, x2, hp[o]);
                hp[o] = fdot2(w3, x3, hp[o]);
            }
        }
#pragma unroll
        for (int o = 0; o < 8; ++o)
            hd[r * 36 + o * 4 + kq] = hp[o];
    }
    LGKM0();

    // ---- final reduce + stores: lane = (row r, o-pair op) ----
    {
        const int r = lane >> 2, op = lane & 3, o0 = op * 2;
        const float ps = psS[wave][r];
        f4v a = *reinterpret_cast<f4v*>(&hd[r * 36 + o0 * 4]);
        f4v b = *reinterpret_cast<f4v*>(&hd[r * 36 + o0 * 4 + 4]);
        float2 ov;
        ov.x = ps * ((a[0] + a[1]) + (a[2] + a[3])) + tbS[wave][r * 8 + o0];
        ov.y = ps * ((b[0] + b[1]) + (b[2] + b[3])) + tbS[wave][r * 8 + o0 + 1];
        const size_t ob = (size_t)(rowbase + r) * OUT_DIM + o0;
        *reinterpret_cast<float2*>(out + ob) = ov;
        const int leaf = lfS[wave][r];
        float2 sv;
        sv.x = fminf(fmaxf(ps * stds[leaf * OUT_DIM + o0],     -20.0f), 2.0f);
        sv.y = fminf(fmaxf(ps * stds[leaf * OUT_DIM + o0 + 1], -20.0f), 2.0f);
        *reinterpret_cast<float2*>(stdo + ob) = sv;
    }
}

extern "C" void kernel_launch(void* const* d_in, const int* in_sizes, int n_in,
                              void* d_out, int out_size, void* d_ws, size_t ws_size,
                              hipStream_t stream) {
    const float* x    = (const float*)d_in[0];
    const float* Wp   = (const float*)d_in[1];
    const float* bp   = (const float*)d_in[2];
    // d_in[3] = Wand -- folded into the traversal, unused.
    const float* Wor  = (const float*)d_in[4];
    const float* bor  = (const float*)d_in[5];
    const float* stds = (const float*)d_in[6];
    float* out = (float*)d_out;

    char* ws = (char*)d_ws;
    _Float16* Wh = (_Float16*)(ws);                    // 512 KB fp16 Wor_t
    _Float16* Bf = (_Float16*)(ws + (512 << 10));      // 64 KB
    _Float16* Bb = (_Float16*)(ws + (576 << 10));      // 4 KB

    prep<<<200, 256, 0, stream>>>(Wor, Wh, Wp, Bf, bor, Bb);
    dgt_main<<<BATCH / 64, 256, 0, stream>>>(x, Wp, bp, Bf, Bb, Wh, stds,
                                             out, out + (size_t)BATCH * OUT_DIM);
}

// Round 17
// 110.308 us; speedup vs baseline: 1.2378x; 1.0261x over previous
//
#include <hip/hip_runtime.h>

#define BATCH 65536
#define IN_DIM 128
#define INT_NODES 255
#define LEAF 256
#define OUT_DIM 8
#define AMB_TH 1.5e-3f  // fp16-GEMM z error ~3e-4 RMS; ~5-sigma guard band

typedef float    f4v __attribute__((ext_vector_type(4)));
typedef _Float16 h8v __attribute__((ext_vector_type(8)));
typedef _Float16 h2v __attribute__((ext_vector_type(2)));

#define LGKM0() __asm__ volatile("s_waitcnt lgkmcnt(0)" ::: "memory")

__device__ __forceinline__ float fdot2(h2v a, h2v b, float c) {
#if __has_builtin(__builtin_amdgcn_fdot2)
    return __builtin_amdgcn_fdot2(a, b, c, false);
#else
    return c + (float)a[0] * (float)b[0] + (float)a[1] * (float)b[1];
#endif
}

// Prepass: blocks [0,64) LDS-tiled transpose Wor -> Wh fp16 [l][o*128+i];
// blocks [64,192) Wp -> fp16 B-frags; blocks [192,200) bor -> fp16 B-frag.
__global__ __launch_bounds__(256) void prep(const float* __restrict__ Wor,
                                            _Float16* __restrict__ Wh,
                                            const float* __restrict__ Wp,
                                            _Float16* __restrict__ Bf,
                                            const float* __restrict__ bor,
                                            _Float16* __restrict__ Bb) {
    if (blockIdx.x < 64) {
        __shared__ float t[64][65];
        const int rt = blockIdx.x >> 2, ct = blockIdx.x & 3;  // 16 x 4 tiles of 64x64
        const int r0 = rt * 64, c0 = ct * 64;
        const int tx = threadIdx.x & 63, ty = threadIdx.x >> 6;
#pragma unroll
        for (int p = 0; p < 16; ++p) {
            int r = ty + p * 4;
            t[r][tx] = Wor[(size_t)(r0 + r) * 256 + c0 + tx];     // coalesced
        }
        __syncthreads();
#pragma unroll
        for (int p = 0; p < 16; ++p) {
            int r = ty + p * 4;
            Wh[(size_t)(c0 + r) * 1024 + r0 + tx] = (_Float16)t[tx][r];  // coalesced
        }
    } else if (blockIdx.x < 192) {
        // B-frag (16x16x32): B[k=ks*32+(lane>>4)*8+j][n=ntg*16+(lane&15)],
        // slot = ((ks*16+ntg)*64+lane)*8+j.
        int slot = (blockIdx.x - 64) * 256 + threadIdx.x;   // 32768
        int j    = slot & 7;
        int lane = (slot >> 3) & 63;
        int ntg  = (slot >> 9) & 15;
        int ks   = slot >> 13;
        int n = ntg * 16 + (lane & 15);
        int k = ks * 32 + (lane >> 4) * 8 + j;
        float v = (n < INT_NODES) ? Wp[n * IN_DIM + k] : 0.f;
        Bf[slot] = (_Float16)v;
    } else {
        // bor B-frag: one 16-col tile (cols 0..7 = outputs), slot=(ks*64+lane)*8+j
        int slot = (blockIdx.x - 192) * 256 + threadIdx.x;  // 2048
        int j    = slot & 7;
        int lane = (slot >> 3) & 63;
        int ks   = slot >> 9;
        int o = lane & 15;
        int k = ks * 32 + (lane >> 4) * 8 + j;
        float v = (o < OUT_DIM) ? bor[o * IN_DIM + k] : 0.f;
        Bb[slot] = (_Float16)v;
    }
}

// Zero-barrier fused main. Wave = 16 rows x 256 nodes, wave-private LDS,
// lgkmcnt-only ordering. fp16 GEMM + fp16 heads gather + bor head via MFMA.
__global__ __launch_bounds__(256) void dgt_main(
    const float* __restrict__ x, const float* __restrict__ Wp,
    const float* __restrict__ bp, const _Float16* __restrict__ Bfg,
    const _Float16* __restrict__ Bbg, const _Float16* __restrict__ Wh,
    const float* __restrict__ stds,
    float* __restrict__ out, float* __restrict__ stdo) {

    __shared__ unsigned char sgnS[4][LEAF * 4];  // [wave][n*4+g]: codes rows g*4+rr
    __shared__ float asumS[4][16 * 16];          // [wave][row*16 + c]
    __shared__ float hdS[4][16 * 36];            // [wave][r*36 + o*4 + kq]
    __shared__ float tbS[4][16 * 8];             // [wave][r*8 + o]: <bor,x>
    __shared__ float psS[4][16];
    __shared__ int   lfS[4][16];

    const int tid  = threadIdx.x;
    const int wave = tid >> 6;
    const int lane = tid & 63;
    const int c = lane & 15;
    const int g = lane >> 4;
    const int rowbase = blockIdx.x * 64 + wave * 16;

    unsigned char* sgn = sgnS[wave];
    float* asum = asumS[wave];
    float* hd = hdS[wave];

    // ---- A-fragments for all 4 k-steps (16 VGPRs) ----
    h8v ah[4];
    {
        const float* xb = x + (size_t)(rowbase + c) * IN_DIM;
#pragma unroll
        for (int ks = 0; ks < 4; ++ks) {
            const float* p = xb + ks * 32 + g * 8;
            float4 v0 = *reinterpret_cast<const float4*>(p);
            float4 v1 = *reinterpret_cast<const float4*>(p + 4);
            h8v a;
            a[0] = (_Float16)v0.x; a[1] = (_Float16)v0.y;
            a[2] = (_Float16)v0.z; a[3] = (_Float16)v0.w;
            a[4] = (_Float16)v1.x; a[5] = (_Float16)v1.y;
            a[6] = (_Float16)v1.z; a[7] = (_Float16)v1.w;
            ah[ks] = a;
        }
    }

    // ---- bor head via MFMA (leaf-independent, reuses ah) ----
    {
        const h8v* Bb8 = (const h8v*)Bbg;
        f4v tb = (f4v){0.f, 0.f, 0.f, 0.f};
#pragma unroll
        for (int ks = 0; ks < 4; ++ks)
            tb = __builtin_amdgcn_mfma_f32_16x16x32_f16(ah[ks], Bb8[ks * 64 + lane], tb, 0, 0, 0);
        if (c < OUT_DIM) {
#pragma unroll
            for (int rr = 0; rr < 4; ++rr)
                tbS[wave][(g * 4 + rr) * 8 + c] = tb[rr];
        }
    }

    // ---- GEMM + compress, two 128-col halves (acc[8] = 32 AGPRs) ----
    const h8v* Bf8 = (const h8v*)Bfg;
    float pp[4] = {0.f, 0.f, 0.f, 0.f};
#pragma unroll
    for (int h = 0; h < 2; ++h) {
        f4v acc[8];
#pragma unroll
        for (int nt = 0; nt < 8; ++nt) acc[nt] = (f4v){0.f, 0.f, 0.f, 0.f};
#pragma unroll
        for (int ks = 0; ks < 4; ++ks)
#pragma unroll
            for (int nt = 0; nt < 8; ++nt) {
                h8v b = Bf8[(ks * 16 + h * 8 + nt) * 64 + lane];  // coalesced, L2-hot
                acc[nt] = __builtin_amdgcn_mfma_f32_16x16x32_f16(ah[ks], b, acc[nt], 0, 0, 0);
            }
        // compress: C/D col n = h*128 + nt*16 + c, row m = g*4 + rr.
        // Col 255 is zero-padded in Bf -> z=0 contributes 0 to the abs-sum,
        // so no n-guard needed on the accumulation (only on the bp read).
#pragma unroll
        for (int nt = 0; nt < 8; ++nt) {
            const int n = h * 128 + nt * 16 + c;
            const float bpv = (n < INT_NODES) ? bp[n] : 0.f;   // 1KB, L1-hot
            unsigned by = 0;
#pragma unroll
            for (int rr = 0; rr < 4; ++rr) {
                float v = acc[nt][rr] + bpv;
                float av = fabsf(v);
                pp[rr] += av;
                by |= ((v < 0.f ? 1u : 0u) | (av < AMB_TH ? 2u : 0u)) << (2 * rr);
            }
            sgn[n * 4 + g] = (unsigned char)by;
        }
    }
#pragma unroll
    for (int rr = 0; rr < 4; ++rr) asum[(g * 4 + rr) * 16 + c] = pp[rr];

    // ---- heads-x prefetch (leaf-independent; overlaps traversal chain) ----
    h2v xh[16];
    {
        const float* xr = x + (size_t)(rowbase + (lane >> 2)) * IN_DIM;
        const int kq = lane & 3;
#pragma unroll
        for (int ch = 0; ch < 4; ++ch) {
            const int base = (ch * 4 + kq) * 8;
            float4 v0 = *reinterpret_cast<const float4*>(xr + base);
            float4 v1 = *reinterpret_cast<const float4*>(xr + base + 4);
            xh[ch * 4 + 0] = (h2v){(_Float16)v0.x, (_Float16)v0.y};
            xh[ch * 4 + 1] = (h2v){(_Float16)v0.z, (_Float16)v0.w};
            xh[ch * 4 + 2] = (h2v){(_Float16)v1.x, (_Float16)v1.y};
            xh[ch * 4 + 3] = (h2v){(_Float16)v1.z, (_Float16)v1.w};
        }
    }
    LGKM0();   // sgn/asum/tb visible (same wave)

    // ---- traversal + p*: lanes 0..15, one row each ----
    if (lane < 16) {
        const int r = lane;
        float s = 0.f;
#pragma unroll
        for (int cc = 0; cc < 16; cc += 4) {
            f4v v = *reinterpret_cast<f4v*>(&asum[r * 16 + cc]);
            s += (v[0] + v[1]) + (v[2] + v[3]);
        }
        const float fac = s * (1.0f / (float)INT_NODES);
        // p* of argmax leaf: sum_l exp(and_z_l - 8 fac) = (1 + e^{-2 fac})^8.
        const float e = expf(-2.0f * fac);
        const float q = 1.0f + e;
        const float q2 = q * q, q4 = q2 * q2, q8 = q4 * q4;

        int node = 0;
#pragma unroll
        for (int d = 0; d < 8; ++d) {
            unsigned by = sgn[node * 4 + (r >> 2)];
            int code = (int)((by >> ((r & 3) * 2)) & 3u);
            int neg;
            if (code & 2) {          // ~1% of rows: exact sign via fp64, 4 chains
                const float* wr = Wp + node * IN_DIM;
                const float* xrow = x + (size_t)(rowbase + r) * IN_DIM;
                double z0 = 0.0, z1 = 0.0, z2 = 0.0, z3 = 0.0;
                for (int k = 0; k < IN_DIM; k += 4) {
                    float4 wv = *reinterpret_cast<const float4*>(wr + k);
                    float4 xv = *reinterpret_cast<const float4*>(xrow + k);
                    z0 = fma((double)wv.x, (double)xv.x, z0);
                    z1 = fma((double)wv.y, (double)xv.y, z1);
                    z2 = fma((double)wv.z, (double)xv.z, z2);
                    z3 = fma((double)wv.w, (double)xv.w, z3);
                }
                double zd = ((z0 + z1) + (z2 + z3)) + (double)bp[node];
                neg = (zd < 0.0) ? 1 : 0;
            } else {
                neg = code & 1;
            }
            node = 2 * node + 1 + neg;
        }
        psS[wave][r] = 1.0f / q8;
        lfS[wave][r] = node - INT_NODES;
    }
    LGKM0();

    // ---- heads: lane = (row r, K-quarter kq); fp16 gather + fdot2.
    //      Chunk (ch*4+kq): 4 kq lanes cover one 64B line of the 2KB slice. ----
    {
        const int r = lane >> 2, kq = lane & 3;
        const int leaf = lfS[wave][r];
        const _Float16* wl = Wh + (size_t)leaf * 1024;
        float hp[8];
#pragma unroll
        for (int o = 0; o < 8; ++o) hp[o] = 0.f;
#pragma unroll
        for (int ch = 0; ch < 4; ++ch) {
            const int base = (ch * 4 + kq) * 8;
            h2v x0 = xh[ch * 4 + 0], x1 = xh[ch * 4 + 1];
            h2v x2 = xh[ch * 4 + 2], x3 = xh[ch * 4 + 3];
#pragma unroll
            for (int o = 0; o < 8; ++o) {
                h8v w8 = *reinterpret_cast<const h8v*>(wl + o * IN_DIM + base);
                h2v w0 = {w8[0], w8[1]}, w1 = {w8[2], w8[3]};
                h2v w2 = {w8[4], w8[5]}, w3 = {w8[6], w8[7]};
                hp[o] = fdot2(w0, x0, hp[o]);
                hp[o] = fdot2(w1, x1, hp[o]);
                hp[o] = fdot2(w2, x2, hp[o]);
                hp[o] = fdot2(w3, x3, hp[o]);
            }
        }
#pragma unroll
        for (int o = 0; o < 8; ++o)
            hd[r * 36 + o * 4 + kq] = hp[o];
    }
    LGKM0();

    // ---- final reduce + stores: lane = (row r, o-pair op) ----
    {
        const int r = lane >> 2, op = lane & 3, o0 = op * 2;
        const float ps = psS[wave][r];
        f4v a = *reinterpret_cast<f4v*>(&hd[r * 36 + o0 * 4]);
        f4v b = *reinterpret_cast<f4v*>(&hd[r * 36 + o0 * 4 + 4]);
        float2 ov;
        ov.x = ps * ((a[0] + a[1]) + (a[2] + a[3])) + tbS[wave][r * 8 + o0];
        ov.y = ps * ((b[0] + b[1]) + (b[2] + b[3])) + tbS[wave][r * 8 + o0 + 1];
        const size_t ob = (size_t)(rowbase + r) * OUT_DIM + o0;
        *reinterpret_cast<float2*>(out + ob) = ov;
        const int leaf = lfS[wave][r];
        float2 sv;
        sv.x = fminf(fmaxf(ps * stds[leaf * OUT_DIM + o0],     -20.0f), 2.0f);
        sv.y = fminf(fmaxf(ps * stds[leaf * OUT_DIM + o0 + 1], -20.0f), 2.0f);
        *reinterpret_cast<float2*>(stdo + ob) = sv;
    }
}

extern "C" void kernel_launch(void* const* d_in, const int* in_sizes, int n_in,
                              void* d_out, int out_size, void* d_ws, size_t ws_size,
                              hipStream_t stream) {
    const float* x    = (const float*)d_in[0];
    const float* Wp   = (const float*)d_in[1];
    const float* bp   = (const float*)d_in[2];
    // d_in[3] = Wand -- folded into the traversal, unused.
    const float* Wor  = (const float*)d_in[4];
    const float* bor  = (const float*)d_in[5];
    const float* stds = (const float*)d_in[6];
    float* out = (float*)d_out;

    char* ws = (char*)d_ws;
    _Float16* Wh = (_Float16*)(ws);                    // 512 KB fp16 Wor_t
    _Float16* Bf = (_Float16*)(ws + (512 << 10));      // 64 KB
    _Float16* Bb = (_Float16*)(ws + (576 << 10));      // 4 KB

    prep<<<200, 256, 0, stream>>>(Wor, Wh, Wp, Bf, bor, Bb);
    dgt_main<<<BATCH / 64, 256, 0, stream>>>(x, Wp, bp, Bf, Bb, Wh, stds,
                                             out, out + (size_t)BATCH * OUT_DIM);
}